// Round 1
// baseline (761.790 us; speedup 1.0000x reference)
//
#include <hip/hip_runtime.h>
#include <hip/hip_bf16.h>
#include <cstddef>

// Problem constants
#define BATCH 65536
#define HDIM  256
#define NGATE 7
#define BH    ((size_t)BATCH * HDIM)

typedef __bf16 bf16x8 __attribute__((ext_vector_type(8)));
typedef __bf16 bf16x4 __attribute__((ext_vector_type(4)));
typedef float  f32x4  __attribute__((ext_vector_type(4)));

// ---------------------------------------------------------------------------
// Kernel 1: convert W (G*H*H fp32) -> bf16 in workspace, same (g,o,h) layout.
// 458752 elements / 4 per thread = 114688 threads = 448 blocks x 256.
// ---------------------------------------------------------------------------
__global__ void __launch_bounds__(256) cvt_w_kernel(const float* __restrict__ W,
                                                    __bf16* __restrict__ Wb) {
    int i = (blockIdx.x * 256 + threadIdx.x) * 4;
    float4 v = *(const float4*)(W + i);
    bf16x4 r;
    r[0] = (__bf16)v.x; r[1] = (__bf16)v.y; r[2] = (__bf16)v.z; r[3] = (__bf16)v.w;
    *(bf16x4*)(Wb + i) = r;
}

// ---------------------------------------------------------------------------
// Fast device math (bf16-level tolerance: ~1e-6 abs error is plenty)
// ---------------------------------------------------------------------------
__device__ __forceinline__ float sigmoidf_(float x) {
    return __builtin_amdgcn_rcpf(1.0f + __expf(-x));
}
__device__ __forceinline__ float tanhf_(float x) {
    // tanh(x) = 1 - 2/(1 + e^{2x}); saturates correctly for large |x|
    return 1.0f - 2.0f * __builtin_amdgcn_rcpf(1.0f + __expf(2.0f * x));
}
__device__ __forceinline__ float softplusf_(float x) {
    // softplus(x) = max(x,0) + log(1 + e^{-|x|})   (numerically stable)
    return fmaxf(x, 0.0f) + __logf(1.0f + __expf(-fabsf(x)));
}

// ---------------------------------------------------------------------------
// Kernel 2: fused 7-gate GEMM (bf16 MFMA 16x16x32) + CT-LSTM epilogue.
// Grid: 1024 blocks x 256 threads. Block = 64 batch rows (4 m-frags of 16).
// Wave w handles o-tiles [4w, 4w+4). All 7 gates accumulated per wave so the
// epilogue mixes gates entirely in registers.
//
// Fragment layouts (verified, cdna_hip_programming.md §3):
//   A[m][k]: m = lane&15, k = (lane>>4)*8 + j   (8 contiguous k -> 16B)
//   B[k][n]: n = lane&15, k = (lane>>4)*8 + j   (W[g] is (o,h) row-major = N x K)
//   C[row][col]: col = lane&15, row = (lane>>4)*4 + reg
// ---------------------------------------------------------------------------
__global__ void __launch_bounds__(256)
fused_ctlstm(const float* __restrict__ inter_times,
             const float* __restrict__ h_ti,
             const float* __restrict__ c_ti,
             const float* __restrict__ cbar,
             const __bf16* __restrict__ Wb,
             const float* __restrict__ bias,
             float* __restrict__ out) {
    const int tid  = threadIdx.x;
    const int lane = tid & 63;
    const int wave = tid >> 6;
    const int col  = lane & 15;
    const int quad = lane >> 4;
    const int m0   = blockIdx.x * 64;

#pragma unroll 1
    for (int ot = 0; ot < 4; ++ot) {
        const int o0 = (wave * 4 + ot) * 16;
        const int o  = o0 + col;

        f32x4 acc[NGATE][4];
#pragma unroll
        for (int g = 0; g < NGATE; ++g)
#pragma unroll
            for (int mf = 0; mf < 4; ++mf)
                acc[g][mf] = (f32x4){0.0f, 0.0f, 0.0f, 0.0f};

#pragma unroll
        for (int ks = 0; ks < 8; ++ks) {
            const int k0 = ks * 32 + quad * 8;

            // A fragments: h_ti rows (fp32 -> bf16 on the fly)
            bf16x8 afrag[4];
#pragma unroll
            for (int mf = 0; mf < 4; ++mf) {
                const float* ap = h_ti + (size_t)(m0 + mf * 16 + col) * HDIM + k0;
                float4 lo = *(const float4*)(ap);
                float4 hi = *(const float4*)(ap + 4);
                afrag[mf][0] = (__bf16)lo.x; afrag[mf][1] = (__bf16)lo.y;
                afrag[mf][2] = (__bf16)lo.z; afrag[mf][3] = (__bf16)lo.w;
                afrag[mf][4] = (__bf16)hi.x; afrag[mf][5] = (__bf16)hi.y;
                afrag[mf][6] = (__bf16)hi.z; afrag[mf][7] = (__bf16)hi.w;
            }

            // B fragments per gate: W[g][o][k0..k0+8) contiguous bf16 (16B)
#pragma unroll
            for (int g = 0; g < NGATE; ++g) {
                bf16x8 bfrag = *(const bf16x8*)(Wb + ((size_t)g * HDIM + o) * HDIM + k0);
#pragma unroll
                for (int mf = 0; mf < 4; ++mf)
                    acc[g][mf] = __builtin_amdgcn_mfma_f32_16x16x32_bf16(
                        afrag[mf], bfrag, acc[g][mf], 0, 0, 0);
            }
        }

        // Bias per gate for this column (loop-invariant over rows)
        float bv[NGATE];
#pragma unroll
        for (int g = 0; g < NGATE; ++g) bv[g] = bias[g * HDIM + o];

        // Epilogue: mix the 7 gates per element, all in registers
#pragma unroll
        for (int mf = 0; mf < 4; ++mf) {
#pragma unroll
            for (int r = 0; r < 4; ++r) {
                const int row = m0 + mf * 16 + quad * 4 + r;
                const size_t idx = (size_t)row * HDIM + o;

                const float i_g  = sigmoidf_(acc[0][mf][r] + bv[0]);
                const float f_g  = sigmoidf_(acc[1][mf][r] + bv[1]);
                const float o_g  = sigmoidf_(acc[2][mf][r] + bv[2]);
                const float ib_g = sigmoidf_(acc[3][mf][r] + bv[3]);
                const float fb_g = sigmoidf_(acc[4][mf][r] + bv[4]);
                const float z    = tanhf_(acc[5][mf][r] + bv[5]);
                const float dec  = softplusf_(acc[6][mf][r] + bv[6]);

                const float dt = inter_times[row];
                const float ct = c_ti[idx];
                const float cb = cbar[idx];

                const float c_after  = cb + (ct - cb) * __expf(-dec * dt);
                const float c_new    = f_g * c_after + i_g * z;
                const float cbar_new = fb_g * cb + ib_g * z;
                const float h_new    = o_g * tanhf_(c_after);

                out[idx]            = o_g;
                out[BH + idx]       = h_new;
                out[2 * BH + idx]   = c_new;
                out[3 * BH + idx]   = cbar_new;
                out[4 * BH + idx]   = dec;
            }
        }
    }
}

// ---------------------------------------------------------------------------
extern "C" void kernel_launch(void* const* d_in, const int* in_sizes, int n_in,
                              void* d_out, int out_size, void* d_ws, size_t ws_size,
                              hipStream_t stream) {
    const float* inter_times = (const float*)d_in[0];
    const float* h_ti        = (const float*)d_in[1];
    const float* c_ti        = (const float*)d_in[2];
    const float* cbar        = (const float*)d_in[3];
    const float* W           = (const float*)d_in[4];
    const float* bias        = (const float*)d_in[5];
    float* out = (float*)d_out;

    __bf16* Wb = (__bf16*)d_ws;  // needs G*H*H*2 = 917504 bytes

    // Convert W to bf16 (458752 elems, 4 per thread)
    cvt_w_kernel<<<(NGATE * HDIM * HDIM) / (256 * 4), 256, 0, stream>>>(W, Wb);

    // Main fused kernel: 65536/64 = 1024 blocks
    fused_ctlstm<<<BATCH / 64, 256, 0, stream>>>(inter_times, h_ti, c_ti, cbar,
                                                 Wb, bias, out);
}